// Round 1
// baseline (1140.798 us; speedup 1.0000x reference)
//
#include <hip/hip_runtime.h>
#include <math.h>

#define BSZ 8
#define NLVL 4
#define E 512
#define H 8
#define D 64
#define FFN 2048
#define NNZ 131072
#define NQ 32            // BSZ*NLVL query rows
#define P32 32           // NLVL*H score planes per batch

// ws layout (float offsets). ints counts_b[8], off_b[8] live at the front.
#define WS_QROT   16
#define WS_WTIL   (WS_QROT + NQ*E)                 // [b][lvl][e][p] : 8*4*512*32
#define WS_WSUM   (WS_WTIL + BSZ*NLVL*E*P32)       // [b][p][e]     : 8*32*512
#define WS_OATT   (WS_WSUM + BSZ*P32*E)            // [r][e]
#define WS_O2     (WS_OATT + NQ*E)
#define WS_Y      (WS_O2 + NQ*E)
#define WS_HID    (WS_Y + NQ*E)                    // [r][f] 32*2048
#define WS_PART   (WS_HID + NQ*FFN)                // [kc32][b][p][e] : 32*8*32*512
#define WS_PLANE  (WS_PART + 32*BSZ*P32*E)         // [p][NNZ]

// ---------------- tiny setup kernels ----------------
__global__ void k_zero(int* wsi) {
    if (blockIdx.x == 0 && threadIdx.x < 8) wsi[threadIdx.x] = 0;
}

__global__ void k_hist(const int* __restrict__ fb, int* wsi) {
    __shared__ int h[8];
    int t = threadIdx.x;
    if (t < 8) h[t] = 0;
    __syncthreads();
    for (int j = blockIdx.x * 256 + t; j < NNZ; j += gridDim.x * 256)
        atomicAdd(&h[fb[j]], 1);
    __syncthreads();
    if (t < 8) atomicAdd(&wsi[t], h[t]);
}

__global__ void k_off(int* wsi) {
    if (threadIdx.x == 0) {
        int run = 0;
        for (int b = 0; b < 8; b++) { wsi[8 + b] = run; run += wsi[b]; }
    }
}

// ---------------- q = rope(LN(bg) @ Wq) ----------------
__global__ void k_qrot(const float* __restrict__ bg, const float* __restrict__ Wq,
                       const float* __restrict__ rf, const float* __restrict__ g,
                       const float* __restrict__ bb, float* __restrict__ ws) {
    __shared__ float xr[E];
    __shared__ float qrow[E];
    __shared__ float red[8];
    int r = blockIdx.x, t = threadIdx.x;
    float v0 = bg[r * E + t], v1 = bg[r * E + t + 256];
    float s = v0 + v1;
    for (int o = 32; o > 0; o >>= 1) s += __shfl_down(s, o, 64);
    if ((t & 63) == 0) red[t >> 6] = s;
    __syncthreads();
    if (t == 0) red[0] = (red[0] + red[1] + red[2] + red[3]) * (1.0f / E);
    __syncthreads();
    float mu = red[0];
    __syncthreads();
    float d0 = v0 - mu, d1 = v1 - mu;
    s = d0 * d0 + d1 * d1;
    for (int o = 32; o > 0; o >>= 1) s += __shfl_down(s, o, 64);
    if ((t & 63) == 0) red[t >> 6] = s;
    __syncthreads();
    if (t == 0) red[0] = rsqrtf((red[0] + red[1] + red[2] + red[3]) * (1.0f / E) + 1e-5f);
    __syncthreads();
    float rstd = red[0];
    xr[t] = d0 * rstd * g[t] + bb[t];
    xr[t + 256] = d1 * rstd * g[t + 256] + bb[t + 256];
    __syncthreads();
    for (int half = 0; half < 2; half++) {
        int c = t + half * 256;
        float acc = 0.f;
        for (int e = 0; e < E; e++) acc += xr[e] * Wq[e * E + c];
        qrow[c] = acc;
    }
    __syncthreads();
    // rope: pair i = t, pos = r//8 (replicates reference's q_lvl = row//bsz quirk)
    int c0 = 2 * t, c1 = c0 + 1;
    int h = c0 >> 6, ii = (c0 & 63) >> 1;
    float freq = rf[h * 32 + ii];
    float pos = (float)(r >> 3);
    float a = pos * freq, ca = cosf(a), sa = sinf(a);
    float x1 = qrow[c0], x2 = qrow[c1];
    float* qr = ws + WS_QROT + r * E;
    qr[c0] = x1 * ca - x2 * sa;
    qr[c1] = x1 * sa + x2 * ca;
}

// ---------------- W~[b][lvl][e][p] = Wk_h @ (R(-lvl)^T... ) * 1/8 ----------------
__global__ void k_wtil(const float* __restrict__ Wkv, const float* __restrict__ rf,
                       float* __restrict__ ws) {
    __shared__ float u[D];
    int blk = blockIdx.x;                 // ((r*4 + lvl)*8 + h)
    int h = blk & 7, lvl = (blk >> 3) & 3, r = blk >> 5;
    int b = r >> 2, l = r & 3;
    int t = threadIdx.x;                  // 64 threads
    const float* qr = ws + WS_QROT + r * E + h * D;
    if (t < 32) {
        float freq = rf[h * 32 + t];
        float a = (float)lvl * freq;
        float ca = cosf(a), sa = sinf(a);
        float x1 = qr[2 * t], x2 = qr[2 * t + 1];
        u[2 * t] = x1 * ca + x2 * sa;      // R(-a) * q_roped
        u[2 * t + 1] = -x1 * sa + x2 * ca;
    }
    __syncthreads();
    float* wt = ws + WS_WTIL + (size_t)((b * NLVL + lvl) * E) * P32;
    int p = l * 8 + h;
    for (int rep = 0; rep < 8; rep++) {
        int e = t + rep * 64;
        const float* wrow = Wkv + (size_t)e * (2 * E) + h * D;
        float acc = 0.f;
#pragma unroll
        for (int c = 0; c < D; c++) acc += wrow[c] * u[c];
        wt[e * P32 + p] = acc * 0.125f;    // fold 1/sqrt(d)
    }
}

// ---------------- scores[p][j] = fv_j . W~[b][lvl_j][:][p] ----------------
__global__ __launch_bounds__(256) void k_scores(
    const float* __restrict__ fv, const int* __restrict__ fb, const int* __restrict__ fl,
    const float* __restrict__ wtil, float* __restrict__ pplane) {
    __shared__ float A[32][256];          // [e_local][key]
    __shared__ float Bm[4][32][32];       // [lvl][e_local][p]
    int t = threadIdx.x;
    int j0 = blockIdx.x * 256;
    int b = fb[j0];                        // batch uniform within 256-key tile
    int kl = t & 31, pq = t >> 5;
    int lv[8];
#pragma unroll
    for (int s = 0; s < 8; s++) lv[s] = fl[j0 + kl + 32 * s];
    float acc[8][4];
#pragma unroll
    for (int s = 0; s < 8; s++) { acc[s][0] = acc[s][1] = acc[s][2] = acc[s][3] = 0.f; }
    const float* wt = wtil + (size_t)b * NLVL * E * P32;
    int arow = t >> 3;
    int aeq = (t & 7) * 4;
    for (int ch = 0; ch < 16; ch++) {
        int e0 = ch * 32;
        __syncthreads();
#pragma unroll
        for (int s = 0; s < 8; s++) {
            int j = s * 32 + arow;
            float4 f4 = *(const float4*)&fv[(size_t)(j0 + j) * E + e0 + aeq];
            A[aeq + 0][j] = f4.x; A[aeq + 1][j] = f4.y;
            A[aeq + 2][j] = f4.z; A[aeq + 3][j] = f4.w;
        }
        {
            int idx = t * 4;
            int be = idx >> 5, bp = idx & 31;
#pragma unroll
            for (int lvv = 0; lvv < 4; lvv++) {
                float4 f4 = *(const float4*)&wt[(size_t)((lvv * E) + e0 + be) * P32 + bp];
                *(float4*)&Bm[lvv][be][bp] = f4;
            }
        }
        __syncthreads();
#pragma unroll
        for (int s = 0; s < 8; s++) {
            int key = kl + 32 * s;
            const float* bmat = &Bm[lv[s]][0][pq * 4];
#pragma unroll 4
            for (int e = 0; e < 32; e++) {
                float a = A[e][key];
                float4 b4 = *(const float4*)&bmat[e * 32];
                acc[s][0] += a * b4.x; acc[s][1] += a * b4.y;
                acc[s][2] += a * b4.z; acc[s][3] += a * b4.w;
            }
        }
    }
#pragma unroll
    for (int s = 0; s < 8; s++) {
        int j = j0 + kl + 32 * s;
#pragma unroll
        for (int q = 0; q < 4; q++) pplane[(size_t)(pq * 4 + q) * NNZ + j] = acc[s][q];
    }
}

// ---------------- softmax per (b, p) over that batch's keys ----------------
__global__ void k_softmax(const int* __restrict__ wsi, const int* __restrict__ maxlen,
                          float* __restrict__ pplane) {
    __shared__ float red[8];
    int b = blockIdx.x >> 5, p = blockIdx.x & 31;
    int t = threadIdx.x;
    int cnt = wsi[b], ml = maxlen[0];
    int n = cnt < ml ? cnt : ml;
    float* base = pplane + (size_t)p * NNZ + wsi[8 + b];
    float m = -1e30f;
    for (int j = t; j < n; j += 256) m = fmaxf(m, base[j]);
    for (int o = 32; o > 0; o >>= 1) m = fmaxf(m, __shfl_down(m, o, 64));
    if ((t & 63) == 0) red[t >> 6] = m;
    __syncthreads();
    if (t == 0) red[0] = fmaxf(fmaxf(red[0], red[1]), fmaxf(red[2], red[3]));
    __syncthreads();
    m = red[0];
    __syncthreads();
    float s = 0.f;
    for (int j = t; j < n; j += 256) s += expf(base[j] - m);
    for (int o = 32; o > 0; o >>= 1) s += __shfl_down(s, o, 64);
    if ((t & 63) == 0) red[t >> 6] = s;
    __syncthreads();
    if (t == 0) red[0] = red[0] + red[1] + red[2] + red[3];
    __syncthreads();
    float inv = 1.0f / red[0];
    for (int j = t; j < n; j += 256) base[j] = expf(base[j] - m) * inv;
}

// ---------------- weighted fv sums: part[kc][b][p][e] = sum_j p[p][j]*fv[j][e] ----------------
__global__ __launch_bounds__(256) void k_pv(
    const float* __restrict__ fv, const float* __restrict__ pplane,
    const int* __restrict__ wsi, const int* __restrict__ maxlen,
    float* __restrict__ part) {
    __shared__ float P[64][36];
    int b = blockIdx.x, kc = blockIdx.y, eh = blockIdx.z;
    int t = threadIdx.x;
    int cnt = wsi[b], ml = maxlen[0];
    int lim = cnt < ml ? cnt : ml;
    int off = wsi[8 + b];
    float acc[32];
#pragma unroll
    for (int p = 0; p < 32; p++) acc[p] = 0.f;
    int k0 = kc * 512;
    int e = eh * 256 + t;
    if (k0 < lim) {
        for (int sub = 0; sub < 8; sub++) {
            int base = k0 + sub * 64;
            int nn = lim - base;
            if (nn <= 0) break;
            if (nn > 64) nn = 64;
            int jj0 = off + base;
            __syncthreads();
            {
                int pp = t >> 3, x = (t & 7) * 8;
#pragma unroll
                for (int q = 0; q < 8; q++) {
                    float pv = (x + q < nn) ? pplane[(size_t)pp * NNZ + jj0 + x + q] : 0.f;
                    P[x + q][pp] = pv;
                }
            }
            __syncthreads();
            for (int k = 0; k < nn; k++) {
                float a = fv[(size_t)(jj0 + k) * E + e];
#pragma unroll
                for (int p4 = 0; p4 < 8; p4++) {
                    float4 pv = *(const float4*)&P[k][p4 * 4];
                    acc[p4 * 4 + 0] += pv.x * a; acc[p4 * 4 + 1] += pv.y * a;
                    acc[p4 * 4 + 2] += pv.z * a; acc[p4 * 4 + 3] += pv.w * a;
                }
            }
        }
    }
    float* dst = part + ((size_t)(kc * BSZ + b) * P32) * E + e;
#pragma unroll
    for (int p = 0; p < 32; p++) dst[(size_t)p * E] = acc[p];
}

__global__ void k_pvred(const float* __restrict__ part, float* __restrict__ wsum) {
    int bp = blockIdx.x;  // b*32+p
    int t = threadIdx.x;
    int b = bp >> 5, p = bp & 31;
    for (int half = 0; half < 2; half++) {
        int e = t + half * 256;
        float s = 0.f;
        for (int kc = 0; kc < 32; kc++)
            s += part[((size_t)(kc * BSZ + b) * P32 + p) * E + e];
        wsum[(size_t)bp * E + e] = s;
    }
}

// ---------------- o_attn[r][c] = wsum[b][l*8+h] . Wv[:, h*64+ch] ----------------
__global__ void k_oproj(const float* __restrict__ wsum, const float* __restrict__ Wkv,
                        float* __restrict__ oatt) {
    __shared__ float Aw[NQ][E];
    int h = blockIdx.x >> 2, ct = blockIdx.x & 3;
    int t = threadIdx.x;
    {
        int rr = t >> 3, x = (t & 7) * 64;
        int row = (rr >> 2) * P32 + (rr & 3) * 8 + h;
#pragma unroll
        for (int q4 = 0; q4 < 16; q4++)
            *(float4*)&Aw[rr][x + q4 * 4] = *(const float4*)&wsum[(size_t)row * E + x + q4 * 4];
    }
    __syncthreads();
#pragma unroll
    for (int rep = 0; rep < 2; rep++) {
        int idx = rep * 256 + t;
        int rr = idx >> 4, cl = idx & 15;
        int c = h * D + ct * 16 + cl;
        float acc = 0.f;
        for (int e = 0; e < E; e++) acc += Aw[rr][e] * Wkv[(size_t)e * (2 * E) + E + c];
        oatt[rr * E + c] = acc;
    }
}

// ---------------- o2 = o_attn @ Wo + bg ----------------
__global__ void k_wo(const float* __restrict__ oatt, const float* __restrict__ Wo,
                     const float* __restrict__ bg, float* __restrict__ o2) {
    __shared__ float Aw[NQ * E];
    int t = threadIdx.x;
#pragma unroll
    for (int q = 0; q < 16; q++) {
        int i = (q * 256 + t) * 4;
        *(float4*)&Aw[i] = *(const float4*)&oatt[i];
    }
    __syncthreads();
    int ct = blockIdx.x;  // 16 blocks of 32 cols
#pragma unroll
    for (int rep = 0; rep < 4; rep++) {
        int idx = rep * 256 + t;
        int rr = idx >> 5, cl = idx & 31;
        int c = ct * 32 + cl;
        float acc = bg[rr * E + c];
        for (int e = 0; e < E; e++) acc += Aw[rr * E + e] * Wo[(size_t)e * E + c];
        o2[rr * E + c] = acc;
    }
}

// ---------------- LN rows of o2 -> y ----------------
__global__ void k_ln2(const float* __restrict__ o2, const float* __restrict__ g,
                      const float* __restrict__ bb, float* __restrict__ y) {
    __shared__ float red[8];
    int r = blockIdx.x, t = threadIdx.x;
    float v0 = o2[r * E + t], v1 = o2[r * E + t + 256];
    float s = v0 + v1;
    for (int o = 32; o > 0; o >>= 1) s += __shfl_down(s, o, 64);
    if ((t & 63) == 0) red[t >> 6] = s;
    __syncthreads();
    if (t == 0) red[0] = (red[0] + red[1] + red[2] + red[3]) * (1.0f / E);
    __syncthreads();
    float mu = red[0];
    __syncthreads();
    float d0 = v0 - mu, d1 = v1 - mu;
    s = d0 * d0 + d1 * d1;
    for (int o = 32; o > 0; o >>= 1) s += __shfl_down(s, o, 64);
    if ((t & 63) == 0) red[t >> 6] = s;
    __syncthreads();
    if (t == 0) red[0] = rsqrtf((red[0] + red[1] + red[2] + red[3]) * (1.0f / E) + 1e-5f);
    __syncthreads();
    float rstd = red[0];
    y[r * E + t] = d0 * rstd * g[t] + bb[t];
    y[r * E + t + 256] = d1 * rstd * g[t + 256] + bb[t + 256];
}

// ---------------- hid = relu(y @ W1 + b1) ----------------
__global__ void k_ffn1(const float* __restrict__ y, const float* __restrict__ W1,
                       const float* __restrict__ b1, float* __restrict__ hid) {
    __shared__ float Aw[NQ * E];
    int t = threadIdx.x;
#pragma unroll
    for (int q = 0; q < 16; q++) {
        int i = (q * 256 + t) * 4;
        *(float4*)&Aw[i] = *(const float4*)&y[i];
    }
    __syncthreads();
    int ft = blockIdx.x;  // 64 blocks of 32 cols
#pragma unroll
    for (int rep = 0; rep < 4; rep++) {
        int idx = rep * 256 + t;
        int rr = idx >> 5, fl = idx & 31;
        int f = ft * 32 + fl;
        float acc = b1[f];
        for (int e = 0; e < E; e++) acc += Aw[rr * E + e] * W1[(size_t)e * FFN + f];
        hid[rr * FFN + f] = fmaxf(acc, 0.f);
    }
}

// ---------------- out = o2 + hid @ W2 + b2 ----------------
__global__ void k_ffn2(const float* __restrict__ hid, const float* __restrict__ W2,
                       const float* __restrict__ b2, const float* __restrict__ o2,
                       float* __restrict__ out) {
    int ct = blockIdx.x;  // 32 blocks of 16 cols
    int t = threadIdx.x;
#pragma unroll
    for (int rep = 0; rep < 2; rep++) {
        int idx = rep * 256 + t;
        int rr = idx >> 4, cl = idx & 15;
        int c = ct * 16 + cl;
        float acc = b2[c] + o2[rr * E + c];
        for (int f = 0; f < FFN; f++) acc += hid[rr * FFN + f] * W2[(size_t)f * E + c];
        out[rr * E + c] = acc;
    }
}

extern "C" void kernel_launch(void* const* d_in, const int* in_sizes, int n_in,
                              void* d_out, int out_size, void* d_ws, size_t ws_size,
                              hipStream_t stream) {
    const float* bg  = (const float*)d_in[0];
    const float* fv  = (const float*)d_in[1];
    const int*   fb  = (const int*)d_in[2];
    const int*   fl  = (const int*)d_in[3];
    const float* Wq  = (const float*)d_in[4];
    const float* Wkv = (const float*)d_in[5];
    const float* Wo  = (const float*)d_in[6];
    const float* rf  = (const float*)d_in[7];
    const float* lag = (const float*)d_in[8];
    const float* lab = (const float*)d_in[9];
    const float* lfg = (const float*)d_in[10];
    const float* lfb = (const float*)d_in[11];
    const float* W1  = (const float*)d_in[12];
    const float* b1  = (const float*)d_in[13];
    const float* W2  = (const float*)d_in[14];
    const float* b2  = (const float*)d_in[15];
    const int* maxlen = (const int*)d_in[16];
    float* ws = (float*)d_ws;
    int* wsi = (int*)d_ws;
    float* out = (float*)d_out;

    hipLaunchKernelGGL(k_zero, dim3(1), dim3(64), 0, stream, wsi);
    hipLaunchKernelGGL(k_hist, dim3(128), dim3(256), 0, stream, fb, wsi);
    hipLaunchKernelGGL(k_off, dim3(1), dim3(64), 0, stream, wsi);
    hipLaunchKernelGGL(k_qrot, dim3(NQ), dim3(256), 0, stream, bg, Wq, rf, lag, lab, ws);
    hipLaunchKernelGGL(k_wtil, dim3(NQ * NLVL * H), dim3(64), 0, stream, Wkv, rf, ws);
    hipLaunchKernelGGL(k_scores, dim3(NNZ / 256), dim3(256), 0, stream,
                       fv, fb, fl, ws + WS_WTIL, ws + WS_PLANE);
    hipLaunchKernelGGL(k_softmax, dim3(BSZ * P32), dim3(256), 0, stream,
                       wsi, maxlen, ws + WS_PLANE);
    hipLaunchKernelGGL(k_pv, dim3(BSZ, 32, 2), dim3(256), 0, stream,
                       fv, ws + WS_PLANE, wsi, maxlen, ws + WS_PART);
    hipLaunchKernelGGL(k_pvred, dim3(BSZ * P32), dim3(256), 0, stream,
                       ws + WS_PART, ws + WS_WSUM);
    hipLaunchKernelGGL(k_oproj, dim3(H * 4), dim3(256), 0, stream,
                       ws + WS_WSUM, Wkv, ws + WS_OATT);
    hipLaunchKernelGGL(k_wo, dim3(16), dim3(256), 0, stream,
                       ws + WS_OATT, Wo, bg, ws + WS_O2);
    hipLaunchKernelGGL(k_ln2, dim3(NQ), dim3(256), 0, stream,
                       ws + WS_O2, lfg, lfb, ws + WS_Y);
    hipLaunchKernelGGL(k_ffn1, dim3(FFN / 32), dim3(256), 0, stream,
                       ws + WS_Y, W1, b1, ws + WS_HID);
    hipLaunchKernelGGL(k_ffn2, dim3(E / 16), dim3(256), 0, stream,
                       ws + WS_HID, W2, b2, ws + WS_O2, out);
}

// Round 2
// 878.954 us; speedup vs baseline: 1.2979x; 1.2979x over previous
//
#include <hip/hip_runtime.h>
#include <hip/hip_bf16.h>
#include <math.h>

#define BSZ 8
#define NLVL 4
#define E 512
#define H 8
#define D 64
#define FFN 2048
#define NNZ 131072
#define NQ 32            // BSZ*NLVL query rows
#define P32 32           // NLVL*H score planes per batch

typedef __attribute__((ext_vector_type(8))) short bf16x8;
typedef __attribute__((ext_vector_type(4))) float f32x4;

// ws layout (float offsets). ints counts_b[8], off_b[8] live at the front.
#define WS_QROT   16
#define WS_WSUM   (WS_QROT + NQ*E)                 // [b][p][e] 8*32*512
#define WS_OATT   (WS_WSUM + BSZ*P32*E)
#define WS_O2     (WS_OATT + NQ*E)
#define WS_Y      (WS_O2 + NQ*E)
#define WS_HID    (WS_Y + NQ*E)                    // [r][f] 32*2048
#define WS_PART   (WS_HID + NQ*FFN)                // [kc32][b][p][e]
#define WS_PLANE  (WS_PART + 32*BSZ*P32*E)         // f32 [p][NNZ]
#define WS_WALL   (WS_PLANE + P32*NNZ)             // bf16 [b][128][512] (float-offset; shorts)
#define WS_PBF    (WS_WALL + BSZ*128*512/2)        // bf16 [p][NNZ]
// total ~11.0M floats = 44 MB

__device__ inline short f2bf(float x) {
    __hip_bfloat16 h = __float2bfloat16(x);
    union { __hip_bfloat16 v; short s; } u; u.v = h; return u.s;
}

__device__ inline bf16x8 cvt8(const float* p) {
    float4 x = *(const float4*)p;
    float4 y = *(const float4*)(p + 4);
    union { bf16x8 v; __hip_bfloat162 h[4]; } u;
    u.h[0] = __float22bfloat162_rn(float2{x.x, x.y});
    u.h[1] = __float22bfloat162_rn(float2{x.z, x.w});
    u.h[2] = __float22bfloat162_rn(float2{y.x, y.y});
    u.h[3] = __float22bfloat162_rn(float2{y.z, y.w});
    return u.v;
}

// ---------------- tiny setup kernels ----------------
__global__ void k_zero(int* wsi) {
    if (blockIdx.x == 0 && threadIdx.x < 8) wsi[threadIdx.x] = 0;
}

__global__ void k_hist(const int* __restrict__ fb, int* wsi) {
    __shared__ int h[8];
    int t = threadIdx.x;
    if (t < 8) h[t] = 0;
    __syncthreads();
    for (int j = blockIdx.x * 256 + t; j < NNZ; j += gridDim.x * 256)
        atomicAdd(&h[fb[j]], 1);
    __syncthreads();
    if (t < 8) atomicAdd(&wsi[t], h[t]);
}

__global__ void k_off(int* wsi) {
    if (threadIdx.x == 0) {
        int run = 0;
        for (int b = 0; b < 8; b++) { wsi[8 + b] = run; run += wsi[b]; }
    }
}

// ---------------- q = rope(LN(bg) @ Wq) ----------------
__global__ void k_qrot(const float* __restrict__ bg, const float* __restrict__ Wq,
                       const float* __restrict__ rf, const float* __restrict__ g,
                       const float* __restrict__ bb, float* __restrict__ ws) {
    __shared__ float xr[E];
    __shared__ float qrow[E];
    __shared__ float red[8];
    int r = blockIdx.x, t = threadIdx.x;
    float v0 = bg[r * E + t], v1 = bg[r * E + t + 256];
    float s = v0 + v1;
    for (int o = 32; o > 0; o >>= 1) s += __shfl_down(s, o, 64);
    if ((t & 63) == 0) red[t >> 6] = s;
    __syncthreads();
    if (t == 0) red[0] = (red[0] + red[1] + red[2] + red[3]) * (1.0f / E);
    __syncthreads();
    float mu = red[0];
    __syncthreads();
    float d0 = v0 - mu, d1 = v1 - mu;
    s = d0 * d0 + d1 * d1;
    for (int o = 32; o > 0; o >>= 1) s += __shfl_down(s, o, 64);
    if ((t & 63) == 0) red[t >> 6] = s;
    __syncthreads();
    if (t == 0) red[0] = rsqrtf((red[0] + red[1] + red[2] + red[3]) * (1.0f / E) + 1e-5f);
    __syncthreads();
    float rstd = red[0];
    xr[t] = d0 * rstd * g[t] + bb[t];
    xr[t + 256] = d1 * rstd * g[t + 256] + bb[t + 256];
    __syncthreads();
    for (int half = 0; half < 2; half++) {
        int c = t + half * 256;
        float acc = 0.f;
        for (int e = 0; e < E; e++) acc += xr[e] * Wq[e * E + c];
        qrow[c] = acc;
    }
    __syncthreads();
    // rope: pos = r//8 (replicates reference's q_lvl = row//bsz quirk)
    int c0 = 2 * t, c1 = c0 + 1;
    int h = c0 >> 6, ii = (c0 & 63) >> 1;
    float freq = rf[h * 32 + ii];
    float pos = (float)(r >> 3);
    float a = pos * freq, ca = cosf(a), sa = sinf(a);
    float x1 = qrow[c0], x2 = qrow[c1];
    float* qr = ws + WS_QROT + r * E;
    qr[c0] = x1 * ca - x2 * sa;
    qr[c1] = x1 * sa + x2 * ca;
}

// ---------------- Wall_bf[b][n=lvl*32+l*8+h][e] = (Wk_h @ R(-lvl) q_roped)/8 ----------------
__global__ void k_wtil(const float* __restrict__ Wkv, const float* __restrict__ rf,
                       const float* __restrict__ ws, short* __restrict__ wall) {
    __shared__ float u[D];
    int blk = blockIdx.x;                 // ((r*4 + lvl)*8 + h)
    int h = blk & 7, lvl = (blk >> 3) & 3, r = blk >> 5;
    int b = r >> 2, l = r & 3;
    int t = threadIdx.x;                  // 64 threads
    const float* qr = ws + WS_QROT + r * E + h * D;
    if (t < 32) {
        float freq = rf[h * 32 + t];
        float a = (float)lvl * freq;
        float ca = cosf(a), sa = sinf(a);
        float x1 = qr[2 * t], x2 = qr[2 * t + 1];
        u[2 * t] = x1 * ca + x2 * sa;      // R(-a) * q_roped
        u[2 * t + 1] = -x1 * sa + x2 * ca;
    }
    __syncthreads();
    int n = lvl * 32 + l * 8 + h;
    short* wrow_out = wall + ((size_t)(b * 128 + n)) * E;
    for (int rep = 0; rep < 8; rep++) {
        int e = t + rep * 64;
        const float* wrow = Wkv + (size_t)e * (2 * E) + h * D;
        float acc = 0.f;
#pragma unroll
        for (int c = 0; c < D; c++) acc += wrow[c] * u[c];
        wrow_out[e] = f2bf(acc * 0.125f);  // fold 1/sqrt(d)
    }
}

// ---------------- scores via MFMA, no LDS ----------------
// Block: 256 thr = 4 waves. Block tile M=128 keys, N=128 (4 lvl x 32 planes), K=512.
// Wave strip: 32 keys (2 m-tiles), 8 n-tiles, 16 k-steps of 32.
// A = fv rows (f32 -> bf16 in-register), B = Wall_bf rows ([n][k], k contiguous).
// Epilogue keeps only the 32 cols matching each key's level -> pplane[p][j].
__global__ __launch_bounds__(256) void k_scores(
    const float* __restrict__ fv, const int* __restrict__ fb, const int* __restrict__ fl,
    const short* __restrict__ wall, float* __restrict__ pplane) {
    int t = threadIdx.x;
    int wave = t >> 6, lane = t & 63, col = lane & 15, quad = lane >> 4;
    int jbase = blockIdx.x * 128;
    int j0 = jbase + wave * 32;
    int b = fb[jbase];                     // 128-tile never crosses a batch (16384-aligned)
    const short* wb = wall + (size_t)b * 128 * E + (size_t)col * E + quad * 8;
    const float* a0 = fv + (size_t)(j0 + col) * E + quad * 8;
    const float* a1 = a0 + (size_t)16 * E;
    f32x4 acc[2][8];
#pragma unroll
    for (int mt = 0; mt < 2; mt++)
#pragma unroll
        for (int nt = 0; nt < 8; nt++) acc[mt][nt] = f32x4{0.f, 0.f, 0.f, 0.f};
    for (int ks = 0; ks < 16; ks++) {
        int e0 = ks * 32;
        bf16x8 bfr[8];
#pragma unroll
        for (int nt = 0; nt < 8; nt++)
            bfr[nt] = *(const bf16x8*)(wb + (size_t)nt * 16 * E + e0);
        bf16x8 af0 = cvt8(a0 + e0);
        bf16x8 af1 = cvt8(a1 + e0);
#pragma unroll
        for (int nt = 0; nt < 8; nt++) {
            acc[0][nt] = __builtin_amdgcn_mfma_f32_16x16x32_bf16(af0, bfr[nt], acc[0][nt], 0, 0, 0);
            acc[1][nt] = __builtin_amdgcn_mfma_f32_16x16x32_bf16(af1, bfr[nt], acc[1][nt], 0, 0, 0);
        }
    }
    // C/D layout: col = lane&15 (n within tile), row = quad*4 + reg (key within tile)
#pragma unroll
    for (int mt = 0; mt < 2; mt++) {
        int kb = j0 + mt * 16 + quad * 4;
#pragma unroll
        for (int r = 0; r < 4; r++) {
            int key = kb + r;
            int lv = fl[key];
#pragma unroll
            for (int nt = 0; nt < 8; nt++) {
                if ((nt >> 1) == lv) {
                    int p = ((nt & 1) << 4) + col;       // n & 31
                    pplane[(size_t)p * NNZ + key] = acc[mt][nt][r];
                }
            }
        }
    }
}

// ---------------- softmax per (b, p); also emit bf16 probs for the PV MFMA ----------------
__global__ void k_softmax(const int* __restrict__ wsi, const int* __restrict__ maxlen,
                          float* __restrict__ pplane, short* __restrict__ pbf) {
    __shared__ float red[8];
    int b = blockIdx.x >> 5, p = blockIdx.x & 31;
    int t = threadIdx.x;
    int cnt = wsi[b], ml = maxlen[0];
    int n = cnt < ml ? cnt : ml;
    int off = wsi[8 + b];
    float* base = pplane + (size_t)p * NNZ + off;
    short* basebf = pbf + (size_t)p * NNZ + off;
    float m = -1e30f;
    for (int j = t; j < n; j += 256) m = fmaxf(m, base[j]);
    for (int o = 32; o > 0; o >>= 1) m = fmaxf(m, __shfl_down(m, o, 64));
    if ((t & 63) == 0) red[t >> 6] = m;
    __syncthreads();
    if (t == 0) red[0] = fmaxf(fmaxf(red[0], red[1]), fmaxf(red[2], red[3]));
    __syncthreads();
    m = red[0];
    __syncthreads();
    float s = 0.f;
    for (int j = t; j < n; j += 256) s += expf(base[j] - m);
    for (int o = 32; o > 0; o >>= 1) s += __shfl_down(s, o, 64);
    if ((t & 63) == 0) red[t >> 6] = s;
    __syncthreads();
    if (t == 0) red[0] = red[0] + red[1] + red[2] + red[3];
    __syncthreads();
    float inv = 1.0f / red[0];
    for (int j = t; j < n; j += 256) {
        float w = expf(base[j] - m) * inv;
        base[j] = w;
        basebf[j] = f2bf(w);
    }
}

// ---------------- PV via MFMA: part[kc][b][p][e] = sum_k P[p][k] * fv[k][e] ----------------
// Grid (b, kc=32 chunks of 512 keys, eh=2 e-halves). Block 256 thr = 4 waves.
// M=32 planes (2 m-tiles), per-wave N=64 e (4 n-tiles), K-step 32 keys.
// A = pbf (bf16, k-contiguous). B = fv transposed per 32-key step through LDS.
#define KP 40   // padded LDS k-stride (shorts): 16B-aligned b128 frags, 2-way read conflicts
__global__ __launch_bounds__(256) void k_pv(
    const float* __restrict__ fv, const short* __restrict__ pbf,
    const int* __restrict__ wsi, const int* __restrict__ maxlen,
    float* __restrict__ part) {
    __shared__ short Bt[256 * KP];
    int t = threadIdx.x;
    int b = blockIdx.x, kc = blockIdx.y, eh = blockIdx.z;
    int cnt = wsi[b], ml = maxlen[0];
    int lim = cnt < ml ? cnt : ml;
    int off = wsi[8 + b];
    int base = kc * 512;
    int wave = t >> 6, lane = t & 63, col = lane & 15, quad = lane >> 4;
    f32x4 acc[2][4];
#pragma unroll
    for (int mt = 0; mt < 2; mt++)
#pragma unroll
        for (int nt = 0; nt < 4; nt++) acc[mt][nt] = f32x4{0.f, 0.f, 0.f, 0.f};
    int nsteps = 0;
    if (base < lim) {
        int r = lim - base;
        nsteps = (r + 31) >> 5;
        if (nsteps > 16) nsteps = 16;
    }
    int sj = (t & 15) * 2;            // key pair within 32-key step
    int se = (t >> 4) * 16;           // 16-e strip within the 256-e half
    const short* ap0 = pbf + (size_t)col * NNZ + off + base + quad * 8;
    const short* ap1 = ap0 + (size_t)16 * NNZ;
    for (int ks = 0; ks < nsteps; ks++) {
        int kbeg = base + ks * 32;
        __syncthreads();
        {   // stage fv[off+kbeg+j][eh*256+e] -> Bt[e*KP + j] as bf16 pairs
            int j0g = off + kbeg + sj;
            int j1g = j0g + 1;
            if (j0g > NNZ - 1) j0g = NNZ - 1;
            if (j1g > NNZ - 1) j1g = NNZ - 1;
            const float* r0 = fv + (size_t)j0g * E + eh * 256 + se;
            const float* r1 = fv + (size_t)j1g * E + eh * 256 + se;
#pragma unroll
            for (int i = 0; i < 4; i++) {
                float4 x0 = *(const float4*)(r0 + i * 4);
                float4 x1 = *(const float4*)(r1 + i * 4);
                const float* f0 = (const float*)&x0;
                const float* f1 = (const float*)&x1;
#pragma unroll
                for (int q = 0; q < 4; q++) {
                    *(__hip_bfloat162*)&Bt[(se + i * 4 + q) * KP + sj] =
                        __float22bfloat162_rn(float2{f0[q], f1[q]});
                }
            }
        }
        __syncthreads();
        int rem = lim - kbeg;
        bf16x8 af0 = *(const bf16x8*)(ap0 + ks * 32);
        bf16x8 af1 = *(const bf16x8*)(ap1 + ks * 32);
        if (rem < 32) {                // tail masking: zero probs for keys >= lim
#pragma unroll
            for (int jj = 0; jj < 8; jj++)
                if (quad * 8 + jj >= rem) { af0[jj] = 0; af1[jj] = 0; }
        }
        const short* bb = &Bt[(wave * 64 + col) * KP + quad * 8];
#pragma unroll
        for (int nt = 0; nt < 4; nt++) {
            bf16x8 bfr = *(const bf16x8*)(bb + nt * 16 * KP);
            acc[0][nt] = __builtin_amdgcn_mfma_f32_16x16x32_bf16(af0, bfr, acc[0][nt], 0, 0, 0);
            acc[1][nt] = __builtin_amdgcn_mfma_f32_16x16x32_bf16(af1, bfr, acc[1][nt], 0, 0, 0);
        }
    }
    float* dst = part + ((size_t)(kc * BSZ + b) * P32) * E + eh * 256;
#pragma unroll
    for (int mt = 0; mt < 2; mt++)
#pragma unroll
        for (int nt = 0; nt < 4; nt++)
#pragma unroll
            for (int r = 0; r < 4; r++) {
                int p = mt * 16 + quad * 4 + r;
                int e = wave * 64 + nt * 16 + col;
                dst[(size_t)p * E + e] = acc[mt][nt][r];
            }
}

__global__ void k_pvred(const float* __restrict__ part, float* __restrict__ wsum) {
    int bp = blockIdx.x;  // b*32+p
    int t = threadIdx.x;
    int b = bp >> 5, p = bp & 31;
    for (int half = 0; half < 2; half++) {
        int e = t + half * 256;
        float s = 0.f;
        for (int kc = 0; kc < 32; kc++)
            s += part[((size_t)(kc * BSZ + b) * P32 + p) * E + e];
        wsum[(size_t)bp * E + e] = s;
    }
}

// ---------------- o_attn[r][c] = wsum[b][l*8+h] . Wv[:, h*64+ch] ----------------
__global__ void k_oproj(const float* __restrict__ wsum, const float* __restrict__ Wkv,
                        float* __restrict__ oatt) {
    __shared__ float Aw[NQ][E];
    int h = blockIdx.x >> 2, ct = blockIdx.x & 3;
    int t = threadIdx.x;
    {
        int rr = t >> 3, x = (t & 7) * 64;
        int row = (rr >> 2) * P32 + (rr & 3) * 8 + h;
#pragma unroll
        for (int q4 = 0; q4 < 16; q4++)
            *(float4*)&Aw[rr][x + q4 * 4] = *(const float4*)&wsum[(size_t)row * E + x + q4 * 4];
    }
    __syncthreads();
#pragma unroll
    for (int rep = 0; rep < 2; rep++) {
        int idx = rep * 256 + t;
        int rr = idx >> 4, cl = idx & 15;
        int c = h * D + ct * 16 + cl;
        float acc = 0.f;
        for (int e = 0; e < E; e++) acc += Aw[rr][e] * Wkv[(size_t)e * (2 * E) + E + c];
        oatt[rr * E + c] = acc;
    }
}

// ---------------- o2 = o_attn @ Wo + bg ----------------
__global__ void k_wo(const float* __restrict__ oatt, const float* __restrict__ Wo,
                     const float* __restrict__ bg, float* __restrict__ o2) {
    __shared__ float Aw[NQ * E];
    int t = threadIdx.x;
#pragma unroll
    for (int q = 0; q < 16; q++) {
        int i = (q * 256 + t) * 4;
        *(float4*)&Aw[i] = *(const float4*)&oatt[i];
    }
    __syncthreads();
    int ct = blockIdx.x;
#pragma unroll
    for (int rep = 0; rep < 4; rep++) {
        int idx = rep * 256 + t;
        int rr = idx >> 5, cl = idx & 31;
        int c = ct * 32 + cl;
        float acc = bg[rr * E + c];
        for (int e = 0; e < E; e++) acc += Aw[rr * E + e] * Wo[(size_t)e * E + c];
        o2[rr * E + c] = acc;
    }
}

// ---------------- LN rows of o2 -> y ----------------
__global__ void k_ln2(const float* __restrict__ o2, const float* __restrict__ g,
                      const float* __restrict__ bb, float* __restrict__ y) {
    __shared__ float red[8];
    int r = blockIdx.x, t = threadIdx.x;
    float v0 = o2[r * E + t], v1 = o2[r * E + t + 256];
    float s = v0 + v1;
    for (int o = 32; o > 0; o >>= 1) s += __shfl_down(s, o, 64);
    if ((t & 63) == 0) red[t >> 6] = s;
    __syncthreads();
    if (t == 0) red[0] = (red[0] + red[1] + red[2] + red[3]) * (1.0f / E);
    __syncthreads();
    float mu = red[0];
    __syncthreads();
    float d0 = v0 - mu, d1 = v1 - mu;
    s = d0 * d0 + d1 * d1;
    for (int o = 32; o > 0; o >>= 1) s += __shfl_down(s, o, 64);
    if ((t & 63) == 0) red[t >> 6] = s;
    __syncthreads();
    if (t == 0) red[0] = rsqrtf((red[0] + red[1] + red[2] + red[3]) * (1.0f / E) + 1e-5f);
    __syncthreads();
    float rstd = red[0];
    y[r * E + t] = d0 * rstd * g[t] + bb[t];
    y[r * E + t + 256] = d1 * rstd * g[t + 256] + bb[t + 256];
}

// ---------------- hid = relu(y @ W1 + b1) ----------------
__global__ void k_ffn1(const float* __restrict__ y, const float* __restrict__ W1,
                       const float* __restrict__ b1, float* __restrict__ hid) {
    __shared__ float Aw[NQ * E];
    int t = threadIdx.x;
#pragma unroll
    for (int q = 0; q < 16; q++) {
        int i = (q * 256 + t) * 4;
        *(float4*)&Aw[i] = *(const float4*)&y[i];
    }
    __syncthreads();
    int ft = blockIdx.x;
#pragma unroll
    for (int rep = 0; rep < 4; rep++) {
        int idx = rep * 256 + t;
        int rr = idx >> 5, fl = idx & 31;
        int f = ft * 32 + fl;
        float acc = b1[f];
        for (int e = 0; e < E; e++) acc += Aw[rr * E + e] * W1[(size_t)e * FFN + f];
        hid[rr * FFN + f] = fmaxf(acc, 0.f);
    }
}

// ---------------- out = o2 + hid @ W2 + b2 ----------------
__global__ void k_ffn2(const float* __restrict__ hid, const float* __restrict__ W2,
                       const float* __restrict__ b2, const float* __restrict__ o2,
                       float* __restrict__ out) {
    int ct = blockIdx.x;
    int t = threadIdx.x;
#pragma unroll
    for (int rep = 0; rep < 2; rep++) {
        int idx = rep * 256 + t;
        int rr = idx >> 4, cl = idx & 15;
        int c = ct * 16 + cl;
        float acc = b2[c] + o2[rr * E + c];
        for (int f = 0; f < FFN; f++) acc += hid[rr * FFN + f] * W2[(size_t)f * E + c];
        out[rr * E + c] = acc;
    }
}

extern "C" void kernel_launch(void* const* d_in, const int* in_sizes, int n_in,
                              void* d_out, int out_size, void* d_ws, size_t ws_size,
                              hipStream_t stream) {
    const float* bg  = (const float*)d_in[0];
    const float* fv  = (const float*)d_in[1];
    const int*   fb  = (const int*)d_in[2];
    const int*   fl  = (const int*)d_in[3];
    const float* Wq  = (const float*)d_in[4];
    const float* Wkv = (const float*)d_in[5];
    const float* Wo  = (const float*)d_in[6];
    const float* rf  = (const float*)d_in[7];
    const float* lag = (const float*)d_in[8];
    const float* lab = (const float*)d_in[9];
    const float* lfg = (const float*)d_in[10];
    const float* lfb = (const float*)d_in[11];
    const float* W1  = (const float*)d_in[12];
    const float* b1  = (const float*)d_in[13];
    const float* W2  = (const float*)d_in[14];
    const float* b2  = (const float*)d_in[15];
    const int* maxlen = (const int*)d_in[16];
    float* ws = (float*)d_ws;
    int* wsi = (int*)d_ws;
    short* wall = (short*)(ws + WS_WALL);
    short* pbf  = (short*)(ws + WS_PBF);
    float* out = (float*)d_out;

    hipLaunchKernelGGL(k_zero, dim3(1), dim3(64), 0, stream, wsi);
    hipLaunchKernelGGL(k_hist, dim3(128), dim3(256), 0, stream, fb, wsi);
    hipLaunchKernelGGL(k_off, dim3(1), dim3(64), 0, stream, wsi);
    hipLaunchKernelGGL(k_qrot, dim3(NQ), dim3(256), 0, stream, bg, Wq, rf, lag, lab, ws);
    hipLaunchKernelGGL(k_wtil, dim3(NQ * NLVL * H), dim3(64), 0, stream, Wkv, rf, ws, wall);
    hipLaunchKernelGGL(k_scores, dim3(NNZ / 128), dim3(256), 0, stream,
                       fv, fb, fl, wall, ws + WS_PLANE);
    hipLaunchKernelGGL(k_softmax, dim3(BSZ * P32), dim3(256), 0, stream,
                       wsi, maxlen, ws + WS_PLANE, pbf);
    hipLaunchKernelGGL(k_pv, dim3(BSZ, 32, 2), dim3(256), 0, stream,
                       fv, pbf, wsi, maxlen, ws + WS_PART);
    hipLaunchKernelGGL(k_pvred, dim3(BSZ * P32), dim3(256), 0, stream,
                       ws + WS_PART, ws + WS_WSUM);
    hipLaunchKernelGGL(k_oproj, dim3(H * 4), dim3(256), 0, stream,
                       ws + WS_WSUM, Wkv, ws + WS_OATT);
    hipLaunchKernelGGL(k_wo, dim3(16), dim3(256), 0, stream,
                       ws + WS_OATT, Wo, bg, ws + WS_O2);
    hipLaunchKernelGGL(k_ln2, dim3(NQ), dim3(256), 0, stream,
                       ws + WS_O2, lfg, lfb, ws + WS_Y);
    hipLaunchKernelGGL(k_ffn1, dim3(FFN / 32), dim3(256), 0, stream,
                       ws + WS_Y, W1, b1, ws + WS_HID);
    hipLaunchKernelGGL(k_ffn2, dim3(E / 16), dim3(256), 0, stream,
                       ws + WS_HID, W2, b2, ws + WS_O2, out);
}

// Round 3
// 864.153 us; speedup vs baseline: 1.3201x; 1.0171x over previous
//
#include <hip/hip_runtime.h>
#include <hip/hip_bf16.h>
#include <math.h>

#define BSZ 8
#define NLVL 4
#define E 512
#define H 8
#define D 64
#define FFN 2048
#define NNZ 131072
#define NQ 32
#define P32 32
#define NEGF -3.0e38f

typedef __attribute__((ext_vector_type(8))) short bf16x8;
typedef __attribute__((ext_vector_type(4))) float f32x4;

// ws layout (float offsets). ints counts_b[8], off_b[8] at front.
#define WS_QROT   16
#define WS_WSUM   (WS_QROT + NQ*E)
#define WS_OATT   (WS_WSUM + BSZ*P32*E)
#define WS_O2     (WS_OATT + NQ*E)
#define WS_Y      (WS_O2 + NQ*E)
#define WS_HID    (WS_Y + NQ*E)
#define WS_PART   (WS_HID + NQ*FFN)          // [512 chunks][32 p][512 e] f32
#define WS_ML     (WS_PART + 512*P32*E)      // [512][32][2] f32
#define WS_WALL   (WS_ML + 512*P32*2)        // bf16 [b][128][512] (shorts)

__device__ inline short f2bf(float x) {
    __hip_bfloat16 h = __float2bfloat16(x);
    union { __hip_bfloat16 v; short s; } u; u.v = h; return u.s;
}

// ---------------- tiny setup kernels ----------------
__global__ void k_zero(int* wsi) {
    if (blockIdx.x == 0 && threadIdx.x < 8) wsi[threadIdx.x] = 0;
}

__global__ void k_hist(const int* __restrict__ fb, int* wsi) {
    __shared__ int h[8];
    int t = threadIdx.x;
    if (t < 8) h[t] = 0;
    __syncthreads();
    for (int j = blockIdx.x * 256 + t; j < NNZ; j += gridDim.x * 256)
        atomicAdd(&h[fb[j]], 1);
    __syncthreads();
    if (t < 8) atomicAdd(&wsi[t], h[t]);
}

__global__ void k_off(int* wsi) {
    if (threadIdx.x == 0) {
        int run = 0;
        for (int b = 0; b < 8; b++) { wsi[8 + b] = run; run += wsi[b]; }
    }
}

// ---------------- q = rope(LN(bg) @ Wq) ----------------
__global__ void k_qrot(const float* __restrict__ bg, const float* __restrict__ Wq,
                       const float* __restrict__ rf, const float* __restrict__ g,
                       const float* __restrict__ bb, float* __restrict__ ws) {
    __shared__ float xr[E];
    __shared__ float qrow[E];
    __shared__ float red[8];
    int r = blockIdx.x, t = threadIdx.x;
    float v0 = bg[r * E + t], v1 = bg[r * E + t + 256];
    float s = v0 + v1;
    for (int o = 32; o > 0; o >>= 1) s += __shfl_down(s, o, 64);
    if ((t & 63) == 0) red[t >> 6] = s;
    __syncthreads();
    if (t == 0) red[0] = (red[0] + red[1] + red[2] + red[3]) * (1.0f / E);
    __syncthreads();
    float mu = red[0];
    __syncthreads();
    float d0 = v0 - mu, d1 = v1 - mu;
    s = d0 * d0 + d1 * d1;
    for (int o = 32; o > 0; o >>= 1) s += __shfl_down(s, o, 64);
    if ((t & 63) == 0) red[t >> 6] = s;
    __syncthreads();
    if (t == 0) red[0] = rsqrtf((red[0] + red[1] + red[2] + red[3]) * (1.0f / E) + 1e-5f);
    __syncthreads();
    float rstd = red[0];
    xr[t] = d0 * rstd * g[t] + bb[t];
    xr[t + 256] = d1 * rstd * g[t + 256] + bb[t + 256];
    __syncthreads();
    for (int half = 0; half < 2; half++) {
        int c = t + half * 256;
        float acc = 0.f;
        for (int e = 0; e < E; e++) acc += xr[e] * Wq[e * E + c];
        qrow[c] = acc;
    }
    __syncthreads();
    int c0 = 2 * t, c1 = c0 + 1;
    int h = c0 >> 6, ii = (c0 & 63) >> 1;
    float freq = rf[h * 32 + ii];
    float pos = (float)(r >> 3);
    float a = pos * freq, ca = cosf(a), sa = sinf(a);
    float x1 = qrow[c0], x2 = qrow[c1];
    float* qr = ws + WS_QROT + r * E;
    qr[c0] = x1 * ca - x2 * sa;
    qr[c1] = x1 * sa + x2 * ca;
}

// ---------------- Wall_bf[b][n=lvl*32+l*8+h][e] ----------------
__global__ void k_wtil(const float* __restrict__ Wkv, const float* __restrict__ rf,
                       const float* __restrict__ ws, short* __restrict__ wall) {
    __shared__ float u[D];
    int blk = blockIdx.x;
    int h = blk & 7, lvl = (blk >> 3) & 3, r = blk >> 5;
    int b = r >> 2, l = r & 3;
    int t = threadIdx.x;
    const float* qr = ws + WS_QROT + r * E + h * D;
    if (t < 32) {
        float freq = rf[h * 32 + t];
        float a = (float)lvl * freq;
        float ca = cosf(a), sa = sinf(a);
        float x1 = qr[2 * t], x2 = qr[2 * t + 1];
        u[2 * t] = x1 * ca + x2 * sa;
        u[2 * t + 1] = -x1 * sa + x2 * ca;
    }
    __syncthreads();
    int n = lvl * 32 + l * 8 + h;
    short* wrow_out = wall + ((size_t)(b * 128 + n)) * E;
    for (int rep = 0; rep < 8; rep++) {
        int e = t + rep * 64;
        const float* wrow = Wkv + (size_t)e * (2 * E) + h * D;
        float acc = 0.f;
#pragma unroll
        for (int c = 0; c < D; c++) acc += wrow[c] * u[c];
        wrow_out[e] = f2bf(acc * 0.125f);
    }
}

// ---------------- fused flash attention over key chunks ----------------
// Grid (b=8, kc=64 chunks of 256 keys). 256 thr = 4 waves.
// Wave w owns: score rows = wall[b][w*32 .. w*32+32) (= level w), PV e-strip [w*128, w*128+128).
// Per 32-key sub-step: stage fv bf16 in [key][e] (scores B) + [e][key] (PV B) LDS layouts;
// scores MFMA; per-plane online max/sum in LDS; P~ assembled bf16 in LDS; PV MFMA.
#define KSTR 520   // kbuf e-stride (shorts)
#define TSTR 40    // fvT/pbuf key-stride (shorts)
__global__ __launch_bounds__(256, 2) void k_flash(
    const float* __restrict__ fv, const int* __restrict__ fl,
    const short* __restrict__ wall, const int* __restrict__ wsi,
    const int* __restrict__ maxlen, float* __restrict__ part, float* __restrict__ ml) {
    __shared__ short kbuf[32 * KSTR];    // [key][e] bf16
    __shared__ short fvT[512 * TSTR];    // [e][key] bf16
    __shared__ short pbuf[32 * TSTR];    // [p][key] bf16
    __shared__ float mbuf[4 * 32];
    __shared__ float lpart[4 * 32];
    __shared__ float alph[32];
    __shared__ float mrun[32];
    __shared__ float lrun[32];

    int t = threadIdx.x;
    int w = t >> 6, lane = t & 63, col = lane & 15, quad = lane >> 4;
    int b = blockIdx.x, kc = blockIdx.y;
    int cnt = wsi[b], mlen = maxlen[0];
    int lim = cnt < mlen ? cnt : mlen;
    int off = wsi[8 + b];
    int kbase = kc * 256;
    int nv = lim - kbase; if (nv > 256) nv = 256; if (nv < 0) nv = 0;

    if (t < 32) { mrun[t] = NEGF; lrun[t] = 0.f; }

    f32x4 acc_o[2][8];
#pragma unroll
    for (int mt = 0; mt < 2; mt++)
#pragma unroll
        for (int nt = 0; nt < 8; nt++) acc_o[mt][nt] = f32x4{0.f, 0.f, 0.f, 0.f};

    const short* wallb = wall + (size_t)b * 128 * E;
    int sj = (t & 15) * 2;
    int se = (t >> 4) * 32;

    for (int s = 0; s < 8; s++) {
        int vs = nv - s * 32;
        if (vs <= 0) break;
        __syncthreads();   // protect fvT/kbuf vs previous sub-step's PV reads
        // ---- S1: stage 32 keys of fv into kbuf + fvT (bf16) ----
        {
            int g0 = off + kbase + s * 32 + sj;
            int g1 = g0 + 1;
            if (g0 > NNZ - 1) g0 = NNZ - 1;
            if (g1 > NNZ - 1) g1 = NNZ - 1;
            const float* r0 = fv + (size_t)g0 * E + se;
            const float* r1 = fv + (size_t)g1 * E + se;
#pragma unroll
            for (int i = 0; i < 8; i++) {
                float4 x0 = *(const float4*)(r0 + i * 4);
                float4 x1 = *(const float4*)(r1 + i * 4);
                int e = se + i * 4;
                *(__hip_bfloat162*)&kbuf[sj * KSTR + e]       = __float22bfloat162_rn(float2{x0.x, x0.y});
                *(__hip_bfloat162*)&kbuf[sj * KSTR + e + 2]   = __float22bfloat162_rn(float2{x0.z, x0.w});
                *(__hip_bfloat162*)&kbuf[(sj+1) * KSTR + e]   = __float22bfloat162_rn(float2{x1.x, x1.y});
                *(__hip_bfloat162*)&kbuf[(sj+1) * KSTR + e+2] = __float22bfloat162_rn(float2{x1.z, x1.w});
                *(__hip_bfloat162*)&fvT[(e + 0) * TSTR + sj] = __float22bfloat162_rn(float2{x0.x, x1.x});
                *(__hip_bfloat162*)&fvT[(e + 1) * TSTR + sj] = __float22bfloat162_rn(float2{x0.y, x1.y});
                *(__hip_bfloat162*)&fvT[(e + 2) * TSTR + sj] = __float22bfloat162_rn(float2{x0.z, x1.z});
                *(__hip_bfloat162*)&fvT[(e + 3) * TSTR + sj] = __float22bfloat162_rn(float2{x0.w, x1.w});
            }
        }
        __syncthreads();
        // ---- S2: scores MFMA: D[wall-row][key], K=512 ----
        f32x4 acc_s[2][2];
#pragma unroll
        for (int mt = 0; mt < 2; mt++)
#pragma unroll
            for (int kt = 0; kt < 2; kt++) acc_s[mt][kt] = f32x4{0.f, 0.f, 0.f, 0.f};
        {
            const short* wr0 = wallb + (size_t)(w * 32 + col) * E + quad * 8;
            const short* wr1 = wr0 + (size_t)16 * E;
            const short* kb0 = &kbuf[col * KSTR + quad * 8];
            const short* kb1 = &kbuf[(16 + col) * KSTR + quad * 8];
#pragma unroll
            for (int ks = 0; ks < 16; ks++) {
                int e0 = ks * 32;
                bf16x8 A0 = *(const bf16x8*)(wr0 + e0);
                bf16x8 A1 = *(const bf16x8*)(wr1 + e0);
                bf16x8 B0 = *(const bf16x8*)(kb0 + e0);
                bf16x8 B1 = *(const bf16x8*)(kb1 + e0);
                acc_s[0][0] = __builtin_amdgcn_mfma_f32_16x16x32_bf16(A0, B0, acc_s[0][0], 0, 0, 0);
                acc_s[0][1] = __builtin_amdgcn_mfma_f32_16x16x32_bf16(A0, B1, acc_s[0][1], 0, 0, 0);
                acc_s[1][0] = __builtin_amdgcn_mfma_f32_16x16x32_bf16(A1, B0, acc_s[1][0], 0, 0, 0);
                acc_s[1][1] = __builtin_amdgcn_mfma_f32_16x16x32_bf16(A1, B1, acc_s[1][1], 0, 0, 0);
            }
        }
        // ---- S3: per-plane sub-step max ----
        int kg0 = off + kbase + s * 32 + col;
        int kg1 = kg0 + 16;
        if (kg0 > NNZ - 1) kg0 = NNZ - 1;
        if (kg1 > NNZ - 1) kg1 = NNZ - 1;
        int lv0 = fl[kg0], lv1 = fl[kg1];
        bool valid0 = (s * 32 + col) < nv;
        bool valid1 = (s * 32 + 16 + col) < nv;
        bool sel0 = valid0 && (lv0 == w);
        bool sel1 = valid1 && (lv1 == w);
#pragma unroll
        for (int mt = 0; mt < 2; mt++) {
#pragma unroll
            for (int r = 0; r < 4; r++) {
                float v0 = sel0 ? acc_s[mt][0][r] : NEGF;
                float v1 = sel1 ? acc_s[mt][1][r] : NEGF;
                float v = fmaxf(v0, v1);
#pragma unroll
                for (int msk = 1; msk < 16; msk <<= 1) v = fmaxf(v, __shfl_xor(v, msk, 16));
                if (col == 0) mbuf[w * 32 + mt * 16 + quad * 4 + r] = v;
            }
        }
        __syncthreads();
        // ---- S4: wave0 lanes<32 update running max, compute alpha ----
        if (t < 32) {
            int p = t;
            float mo = mrun[p];
            float mn = mo;
            mn = fmaxf(mn, mbuf[p]);
            mn = fmaxf(mn, mbuf[32 + p]);
            mn = fmaxf(mn, mbuf[64 + p]);
            mn = fmaxf(mn, mbuf[96 + p]);
            alph[p] = expf(mo - mn);
            mrun[p] = mn;
        }
        __syncthreads();
        // ---- S5: P~ = exp(s - m), assemble in pbuf; partial l; rescale O ----
        float mr[2][4], ar[2][4];
#pragma unroll
        for (int mt = 0; mt < 2; mt++)
#pragma unroll
            for (int r = 0; r < 4; r++) {
                int p = mt * 16 + quad * 4 + r;
                mr[mt][r] = mrun[p];
                ar[mt][r] = alph[p];
            }
#pragma unroll
        for (int mt = 0; mt < 2; mt++) {
#pragma unroll
            for (int r = 0; r < 4; r++) {
                int p = mt * 16 + quad * 4 + r;
                float ls = 0.f;
                {
                    if (sel0) {
                        float pv = expf(acc_s[mt][0][r] - mr[mt][r]);
                        pbuf[p * TSTR + col] = f2bf(pv);
                        ls += pv;
                    } else if (w == 0 && !valid0) {
                        pbuf[p * TSTR + col] = 0;
                    }
                    if (sel1) {
                        float pv = expf(acc_s[mt][1][r] - mr[mt][r]);
                        pbuf[p * TSTR + 16 + col] = f2bf(pv);
                        ls += pv;
                    } else if (w == 0 && !valid1) {
                        pbuf[p * TSTR + 16 + col] = 0;
                    }
                }
#pragma unroll
                for (int msk = 1; msk < 16; msk <<= 1) ls += __shfl_xor(ls, msk, 16);
                if (col == 0) lpart[w * 32 + p] = ls;
            }
        }
        // rescale O accumulators by alpha
#pragma unroll
        for (int mt = 0; mt < 2; mt++)
#pragma unroll
            for (int nt = 0; nt < 8; nt++)
#pragma unroll
                for (int r = 0; r < 4; r++) acc_o[mt][nt][r] *= ar[mt][r];
        __syncthreads();
        // ---- S6: PV MFMA: O[p][e] += P~ @ fvT, K=32 keys ----
        {
            bf16x8 Ap0 = *(const bf16x8*)&pbuf[col * TSTR + quad * 8];
            bf16x8 Ap1 = *(const bf16x8*)&pbuf[(16 + col) * TSTR + quad * 8];
            const short* bt = &fvT[(size_t)(w * 128 + col) * TSTR + quad * 8];
#pragma unroll
            for (int nt = 0; nt < 8; nt++) {
                bf16x8 Bf = *(const bf16x8*)(bt + (size_t)nt * 16 * TSTR);
                acc_o[0][nt] = __builtin_amdgcn_mfma_f32_16x16x32_bf16(Ap0, Bf, acc_o[0][nt], 0, 0, 0);
                acc_o[1][nt] = __builtin_amdgcn_mfma_f32_16x16x32_bf16(Ap1, Bf, acc_o[1][nt], 0, 0, 0);
            }
        }
        // ---- S7: wave0 updates running l (safe: next write to lpart is after 3 barriers) ----
        if (t < 32) {
            int p = t;
            lrun[p] = lrun[p] * alph[p] + (lpart[p] + lpart[32 + p] + lpart[64 + p] + lpart[96 + p]);
        }
    }
    // ---- epilogue: write partial O and (m,l) ----
    size_t pbase = ((size_t)(b * 64 + kc) * P32) * E;
#pragma unroll
    for (int mt = 0; mt < 2; mt++)
#pragma unroll
        for (int r = 0; r < 4; r++) {
            int p = mt * 16 + quad * 4 + r;
#pragma unroll
            for (int nt = 0; nt < 8; nt++) {
                int e = w * 128 + nt * 16 + col;
                part[pbase + (size_t)p * E + e] = acc_o[mt][nt][r];
            }
        }
    if (t < 32) {
        size_t idx = (size_t)(b * 64 + kc) * P32 + t;
        ml[idx * 2] = mrun[t];
        ml[idx * 2 + 1] = lrun[t];
    }
}

// ---------------- merge chunk partials (log-sum-exp) -> wsum[b*32+p][e] ----------------
__global__ void k_merge(const float* __restrict__ part, const float* __restrict__ ml,
                        float* __restrict__ wsum) {
    __shared__ float wexp[64];
    int b = blockIdx.x >> 5, p = blockIdx.x & 31;
    int t = threadIdx.x;
    float M = NEGF;
    for (int kc = 0; kc < 64; kc++)
        M = fmaxf(M, ml[((size_t)(b * 64 + kc) * P32 + p) * 2]);
    float denom = 0.f;
    for (int kc = 0; kc < 64; kc++) {
        size_t idx = ((size_t)(b * 64 + kc) * P32 + p) * 2;
        denom += ml[idx + 1] * expf(ml[idx] - M);
    }
    if (t < 64)
        wexp[t] = expf(ml[((size_t)(b * 64 + t) * P32 + p) * 2] - M);
    __syncthreads();
    float inv = 1.0f / denom;
    for (int half = 0; half < 2; half++) {
        int e = t + half * 256;
        float acc = 0.f;
        for (int kc = 0; kc < 64; kc++)
            acc += part[((size_t)(b * 64 + kc) * P32 + p) * E + e] * wexp[kc];
        wsum[((size_t)(b * P32 + p)) * E + e] = acc * inv;
    }
}

// ---------------- o_attn[r][c] = wsum[b][l*8+h] . Wv[:, h*64+ch] ----------------
__global__ void k_oproj(const float* __restrict__ wsum, const float* __restrict__ Wkv,
                        float* __restrict__ oatt) {
    __shared__ float Aw[NQ][E];
    int h = blockIdx.x >> 2, ct = blockIdx.x & 3;
    int t = threadIdx.x;
    {
        int rr = t >> 3, x = (t & 7) * 64;
        int row = (rr >> 2) * P32 + (rr & 3) * 8 + h;
#pragma unroll
        for (int q4 = 0; q4 < 16; q4++)
            *(float4*)&Aw[rr][x + q4 * 4] = *(const float4*)&wsum[(size_t)row * E + x + q4 * 4];
    }
    __syncthreads();
#pragma unroll
    for (int rep = 0; rep < 2; rep++) {
        int idx = rep * 256 + t;
        int rr = idx >> 4, cl = idx & 15;
        int c = h * D + ct * 16 + cl;
        float acc = 0.f;
        for (int e = 0; e < E; e++) acc += Aw[rr][e] * Wkv[(size_t)e * (2 * E) + E + c];
        oatt[rr * E + c] = acc;
    }
}

// ---------------- o2 = o_attn @ Wo + bg ----------------
__global__ void k_wo(const float* __restrict__ oatt, const float* __restrict__ Wo,
                     const float* __restrict__ bg, float* __restrict__ o2) {
    __shared__ float Aw[NQ * E];
    int t = threadIdx.x;
#pragma unroll
    for (int q = 0; q < 16; q++) {
        int i = (q * 256 + t) * 4;
        *(float4*)&Aw[i] = *(const float4*)&oatt[i];
    }
    __syncthreads();
    int ct = blockIdx.x;
#pragma unroll
    for (int rep = 0; rep < 4; rep++) {
        int idx = rep * 256 + t;
        int rr = idx >> 5, cl = idx & 31;
        int c = ct * 32 + cl;
        float acc = bg[rr * E + c];
        for (int e = 0; e < E; e++) acc += Aw[rr * E + e] * Wo[(size_t)e * E + c];
        o2[rr * E + c] = acc;
    }
}

// ---------------- LN rows of o2 -> y ----------------
__global__ void k_ln2(const float* __restrict__ o2, const float* __restrict__ g,
                      const float* __restrict__ bb, float* __restrict__ y) {
    __shared__ float red[8];
    int r = blockIdx.x, t = threadIdx.x;
    float v0 = o2[r * E + t], v1 = o2[r * E + t + 256];
    float s = v0 + v1;
    for (int o = 32; o > 0; o >>= 1) s += __shfl_down(s, o, 64);
    if ((t & 63) == 0) red[t >> 6] = s;
    __syncthreads();
    if (t == 0) red[0] = (red[0] + red[1] + red[2] + red[3]) * (1.0f / E);
    __syncthreads();
    float mu = red[0];
    __syncthreads();
    float d0 = v0 - mu, d1 = v1 - mu;
    s = d0 * d0 + d1 * d1;
    for (int o = 32; o > 0; o >>= 1) s += __shfl_down(s, o, 64);
    if ((t & 63) == 0) red[t >> 6] = s;
    __syncthreads();
    if (t == 0) red[0] = rsqrtf((red[0] + red[1] + red[2] + red[3]) * (1.0f / E) + 1e-5f);
    __syncthreads();
    float rstd = red[0];
    y[r * E + t] = d0 * rstd * g[t] + bb[t];
    y[r * E + t + 256] = d1 * rstd * g[t + 256] + bb[t + 256];
}

// ---------------- hid = relu(y @ W1 + b1) ----------------
__global__ void k_ffn1(const float* __restrict__ y, const float* __restrict__ W1,
                       const float* __restrict__ b1, float* __restrict__ hid) {
    __shared__ float Aw[NQ * E];
    int t = threadIdx.x;
#pragma unroll
    for (int q = 0; q < 16; q++) {
        int i = (q * 256 + t) * 4;
        *(float4*)&Aw[i] = *(const float4*)&y[i];
    }
    __syncthreads();
    int ft = blockIdx.x;
#pragma unroll
    for (int rep = 0; rep < 4; rep++) {
        int idx = rep * 256 + t;
        int rr = idx >> 5, fl = idx & 31;
        int f = ft * 32 + fl;
        float acc = b1[f];
        for (int e = 0; e < E; e++) acc += Aw[rr * E + e] * W1[(size_t)e * FFN + f];
        hid[rr * FFN + f] = fmaxf(acc, 0.f);
    }
}

// ---------------- out = o2 + hid @ W2 + b2 ----------------
__global__ void k_ffn2(const float* __restrict__ hid, const float* __restrict__ W2,
                       const float* __restrict__ b2, const float* __restrict__ o2,
                       float* __restrict__ out) {
    int ct = blockIdx.x;
    int t = threadIdx.x;
#pragma unroll
    for (int rep = 0; rep < 2; rep++) {
        int idx = rep * 256 + t;
        int rr = idx >> 4, cl = idx & 15;
        int c = ct * 16 + cl;
        float acc = b2[c] + o2[rr * E + c];
        for (int f = 0; f < FFN; f++) acc += hid[rr * FFN + f] * W2[(size_t)f * E + c];
        out[rr * E + c] = acc;
    }
}

extern "C" void kernel_launch(void* const* d_in, const int* in_sizes, int n_in,
                              void* d_out, int out_size, void* d_ws, size_t ws_size,
                              hipStream_t stream) {
    const float* bg  = (const float*)d_in[0];
    const float* fv  = (const float*)d_in[1];
    const int*   fb  = (const int*)d_in[2];
    const int*   fl  = (const int*)d_in[3];
    const float* Wq  = (const float*)d_in[4];
    const float* Wkv = (const float*)d_in[5];
    const float* Wo  = (const float*)d_in[6];
    const float* rf  = (const float*)d_in[7];
    const float* lag = (const float*)d_in[8];
    const float* lab = (const float*)d_in[9];
    const float* lfg = (const float*)d_in[10];
    const float* lfb = (const float*)d_in[11];
    const float* W1  = (const float*)d_in[12];
    const float* b1  = (const float*)d_in[13];
    const float* W2  = (const float*)d_in[14];
    const float* b2  = (const float*)d_in[15];
    const int* maxlen = (const int*)d_in[16];
    float* ws = (float*)d_ws;
    int* wsi = (int*)d_ws;
    short* wall = (short*)(ws + WS_WALL);
    float* out = (float*)d_out;

    hipLaunchKernelGGL(k_zero, dim3(1), dim3(64), 0, stream, wsi);
    hipLaunchKernelGGL(k_hist, dim3(128), dim3(256), 0, stream, fb, wsi);
    hipLaunchKernelGGL(k_off, dim3(1), dim3(64), 0, stream, wsi);
    hipLaunchKernelGGL(k_qrot, dim3(NQ), dim3(256), 0, stream, bg, Wq, rf, lag, lab, ws);
    hipLaunchKernelGGL(k_wtil, dim3(NQ * NLVL * H), dim3(64), 0, stream, Wkv, rf, ws, wall);
    hipLaunchKernelGGL(k_flash, dim3(BSZ, 64), dim3(256), 0, stream,
                       fv, fl, wall, wsi, maxlen, ws + WS_PART, ws + WS_ML);
    hipLaunchKernelGGL(k_merge, dim3(BSZ * P32), dim3(256), 0, stream,
                       ws + WS_PART, ws + WS_ML, ws + WS_WSUM);
    hipLaunchKernelGGL(k_oproj, dim3(H * 4), dim3(256), 0, stream,
                       ws + WS_WSUM, Wkv, ws + WS_OATT);
    hipLaunchKernelGGL(k_wo, dim3(16), dim3(256), 0, stream,
                       ws + WS_OATT, Wo, bg, ws + WS_O2);
    hipLaunchKernelGGL(k_ln2, dim3(NQ), dim3(256), 0, stream,
                       ws + WS_O2, lfg, lfb, ws + WS_Y);
    hipLaunchKernelGGL(k_ffn1, dim3(FFN / 32), dim3(256), 0, stream,
                       ws + WS_Y, W1, b1, ws + WS_HID);
    hipLaunchKernelGGL(k_ffn2, dim3(E / 16), dim3(256), 0, stream,
                       ws + WS_HID, W2, b2, ws + WS_O2, out);
}